// Round 2
// baseline (2912.523 us; speedup 1.0000x reference)
//
#include <hip/hip_runtime.h>
#include <math.h>

// Problem constants
#define NB    2048
#define D0    289          // N0
#define D1    100          // N1
#define D2    25           // N2
#define KPAD  320          // D0 padded to multiple of 32
#define WLD   104          // padded row length for W1T / T1T tiles (104*4=416B)
#define X_ELE ((size_t)D0*D0)   // 83521

// ---------------------------------------------------------------------------
// prep: W1T_pad[k][o] = W1[o][k], zero-padded to [320][104]
__global__ __launch_bounds__(256) void prep_w1t(const float* __restrict__ W1,
                                                float* __restrict__ W1T) {
    int idx = blockIdx.x * 256 + threadIdx.x;          // 130 blocks * 256 = 33280
    int k = idx / WLD, o = idx % WLD;
    W1T[idx] = (k < D0 && o < D1) ? W1[o * D0 + k] : 0.0f;
}

// ---------------------------------------------------------------------------
// K1: T1T[b][n][m] = (W1 @ X[b])[m][n]   (M=100 exact, N=289 in 4 tiles of 80, K=320)
// block 256: compute threads 250 = 25(m-groups of 4, stride 25) x 10(n-groups of 8).
// Output written TRANSPOSED, zero-padded to [320][104] so K2 needs no masking.
__global__ __launch_bounds__(256) void k1_wx(const float* __restrict__ X,
                                             const float* __restrict__ W1T,
                                             float* __restrict__ T1T) {
    const int bb = blockIdx.x;
    const int n0 = blockIdx.y * 80;
    const int tid = threadIdx.x;
    const int tm = tid % 25;           // m in {tm, tm+25, tm+50, tm+75}
    const int tn = tid / 25;           // n-group (valid when tid < 250)

    __shared__ __align__(16) float Ws[32 * WLD];   // [kk][m]  13.3 KB
    __shared__ __align__(16) float Xs[32 * 84];    // [kk][c]  10.5 KB

    const float* Xb = X + (size_t)bb * X_ELE;

    float acc[4][8];
#pragma unroll
    for (int e = 0; e < 4; ++e)
#pragma unroll
        for (int j = 0; j < 8; ++j) acc[e][j] = 0.0f;

    for (int kt = 0; kt < 10; ++kt) {
        const int k0 = kt * 32;
        // stage W1T tile: 32*104 = 3328 floats, flat coalesced (already padded)
#pragma unroll
        for (int i = 0; i < 13; ++i) {
            int f = tid + 256 * i;
            Ws[f] = W1T[k0 * WLD + f];
        }
        // stage X tile: 32 rows x 80 cols, zero-fill outside [289,289]
#pragma unroll
        for (int i = 0; i < 10; ++i) {
            int f = tid + 256 * i;                  // < 2560
            int r = f / 80, cc = f % 80;
            int k = k0 + r, col = n0 + cc;
            float v = (k < D0 && col < D0) ? Xb[(size_t)k * D0 + col] : 0.0f;
            Xs[r * 84 + cc] = v;
        }
        __syncthreads();
        if (tid < 250) {
#pragma unroll
            for (int kk = 0; kk < 32; ++kk) {
                const float4 x0 = *(const float4*)&Xs[kk * 84 + tn * 8];
                const float4 x1 = *(const float4*)&Xs[kk * 84 + tn * 8 + 4];
                float w[4];
#pragma unroll
                for (int e = 0; e < 4; ++e) w[e] = Ws[kk * WLD + tm + 25 * e];
#pragma unroll
                for (int e = 0; e < 4; ++e) {
                    acc[e][0] += w[e] * x0.x;
                    acc[e][1] += w[e] * x0.y;
                    acc[e][2] += w[e] * x0.z;
                    acc[e][3] += w[e] * x0.w;
                    acc[e][4] += w[e] * x1.x;
                    acc[e][5] += w[e] * x1.y;
                    acc[e][6] += w[e] * x1.z;
                    acc[e][7] += w[e] * x1.w;
                }
            }
        }
        __syncthreads();
    }
    if (tid < 250) {
        float* Tb = T1T + (size_t)bb * ((size_t)KPAD * WLD);
#pragma unroll
        for (int j = 0; j < 8; ++j) {
            int n = n0 + tn * 8 + j;               // n < 320; pad rows get exact zeros
#pragma unroll
            for (int e = 0; e < 4; ++e)
                Tb[n * WLD + tm + 25 * e] = acc[e][j];
        }
    }
}

// ---------------------------------------------------------------------------
// K2: S1[b] = sinh(T1[b] @ W1^T)  (100x100, K=320, mask-free: both operands
// pre-transposed + zero-padded in [320][104] layout)
__global__ __launch_bounds__(256) void k2_tw(const float* __restrict__ T1T,
                                             const float* __restrict__ W1T,
                                             float* __restrict__ S1) {
    const int bb = blockIdx.x;
    const int tid = threadIdx.x;
    const int tm = tid % 25;           // m in {tm, tm+25, tm+50, tm+75}
    const int tn = tid / 25;           // n-group of 10 (valid when tid < 250)

    __shared__ __align__(16) float At[32 * WLD];   // [kk][m] 13.3 KB
    __shared__ __align__(16) float Bt[32 * WLD];   // [kk][p] 13.3 KB

    const float* Tb = T1T + (size_t)bb * ((size_t)KPAD * WLD);

    float acc[4][10];
#pragma unroll
    for (int e = 0; e < 4; ++e)
#pragma unroll
        for (int j = 0; j < 10; ++j) acc[e][j] = 0.0f;

    for (int kt = 0; kt < 10; ++kt) {
        const int k0 = kt * 32;
#pragma unroll
        for (int i = 0; i < 13; ++i) {            // flat coalesced, no branches
            int f = tid + 256 * i;
            At[f] = Tb[k0 * WLD + f];
            Bt[f] = W1T[k0 * WLD + f];
        }
        __syncthreads();
        if (tid < 250) {
#pragma unroll
            for (int kk = 0; kk < 32; ++kk) {
                float a[4];
#pragma unroll
                for (int e = 0; e < 4; ++e) a[e] = At[kk * WLD + tm + 25 * e];
                float b[10];
#pragma unroll
                for (int h = 0; h < 5; ++h) {
                    float2 bp = *(const float2*)&Bt[kk * WLD + tn * 10 + 2 * h];
                    b[2 * h] = bp.x; b[2 * h + 1] = bp.y;
                }
#pragma unroll
                for (int e = 0; e < 4; ++e)
#pragma unroll
                    for (int j = 0; j < 10; ++j) acc[e][j] += a[e] * b[j];
            }
        }
        __syncthreads();
    }
    if (tid < 250) {
        float* Sb = S1 + (size_t)bb * (D1 * D1);
#pragma unroll
        for (int e = 0; e < 4; ++e) {
            int m = tm + 25 * e;
#pragma unroll
            for (int j = 0; j < 10; ++j)
                Sb[m * D1 + tn * 10 + j] = sinhf(acc[e][j]);
        }
    }
}

// ---------------------------------------------------------------------------
// K3: A2[b] = sinh(W2 @ S1[b] @ W2^T)   (tiny: 25x25 out, K=100)
__global__ __launch_bounds__(256) void k3_bimap2(const float* __restrict__ S1,
                                                 const float* __restrict__ W2,
                                                 float* __restrict__ A2) {
    __shared__ float S1s[D1 * 101];   // 40.4 KB
    __shared__ float W2s[D2 * D1];    // 10 KB
    __shared__ float T2s[D2 * WLD];   // 10.4 KB
    const int bb = blockIdx.x;
    const int tid = threadIdx.x;
    const float* Sb = S1 + (size_t)bb * (D1 * D1);

    for (int f = tid; f < D1 * D1; f += 256) {
        int i = f / D1, j = f % D1;
        S1s[i * 101 + j] = Sb[f];
    }
    for (int f = tid; f < D2 * D1; f += 256) W2s[f] = W2[f];
    __syncthreads();

    if (tid < 250) {                          // T2 = W2 @ S1 : 25 x 100
        int o = tid / 10, jg = tid % 10;
        float t2[10];
#pragma unroll
        for (int j = 0; j < 10; ++j) t2[j] = 0.0f;
        for (int i = 0; i < D1; ++i) {
            float w = W2s[o * D1 + i];
#pragma unroll
            for (int j = 0; j < 10; ++j) t2[j] += w * S1s[i * 101 + jg * 10 + j];
        }
#pragma unroll
        for (int j = 0; j < 10; ++j) T2s[o * WLD + jg * 10 + j] = t2[j];
    }
    __syncthreads();

    for (int f = tid; f < D2 * D2; f += 256) {  // Y2 = T2 @ W2^T, sinh
        int o = f / D2, p = f % D2;
        float a = 0.0f;
        for (int i = 0; i < D1; ++i) a += T2s[o * WLD + i] * W2s[p * D1 + i];
        A2[(size_t)bb * (D2 * D2) + f] = sinhf(a);
    }
}

// ---------------------------------------------------------------------------
// K4: batched 25x25 symmetric Jacobi eigensolve + U log(L) U^T
// one 64-thread block per matrix; parallel-order (tournament) cyclic Jacobi.
#define SWEEPS 9
__global__ __launch_bounds__(64) void k4_logeig(const float* __restrict__ A2,
                                                float* __restrict__ out) {
    __shared__ float A[D2 * 26];
    __shared__ float U[D2 * 26];
    __shared__ float cs[13 * 2];
    __shared__ float lg[D2];
    const int b = blockIdx.x;
    const int t = threadIdx.x;
    const float* G = A2 + (size_t)b * (D2 * D2);

    for (int f = t; f < D2 * 26; f += 64) {
        int i = f / 26, j = f % 26;
        if (j < D2) {
            A[f] = 0.5f * (G[i * D2 + j] + G[j * D2 + i]);   // symmetrize
            U[f] = (i == j) ? 1.0f : 0.0f;
        } else { A[f] = 0.0f; U[f] = 0.0f; }
    }
    __syncthreads();

    for (int sw = 0; sw < SWEEPS; ++sw) {
        for (int r = 0; r < 25; ++r) {
            if (t >= 1 && t <= 12) {
                int p = (r + t) % 25, q = (r + 25 - t) % 25;
                float app = A[p * 26 + p], aqq = A[q * 26 + q], apq = A[p * 26 + q];
                float c = 1.0f, s = 0.0f;
                if (fabsf(apq) > 1e-30f) {
                    float tau = (aqq - app) / (2.0f * apq);
                    float sq = sqrtf(1.0f + tau * tau);
                    float tt = (tau >= 0.0f) ? 1.0f / (tau + sq) : 1.0f / (tau - sq);
                    c = 1.0f / sqrtf(1.0f + tt * tt);
                    s = tt * c;
                }
                cs[t * 2] = c; cs[t * 2 + 1] = s;
            }
            __syncthreads();
            // row updates: A <- J^T A   (12 pairs x 25 cols)
            for (int idx = t; idx < 300; idx += 64) {
                int pi = idx / 25 + 1, j = idx % 25;
                int p = (r + pi) % 25, q = (r + 25 - pi) % 25;
                float c = cs[pi * 2], s = cs[pi * 2 + 1];
                float ap = A[p * 26 + j], aq = A[q * 26 + j];
                A[p * 26 + j] = c * ap - s * aq;
                A[q * 26 + j] = s * ap + c * aq;
            }
            __syncthreads();
            // col updates: A <- A J, U <- U J   (12 pairs x 25 rows, x2 matrices)
            for (int idx = t; idx < 600; idx += 64) {
                int pi = (idx % 300) / 25 + 1, i = idx % 25;
                int p = (r + pi) % 25, q = (r + 25 - pi) % 25;
                float c = cs[pi * 2], s = cs[pi * 2 + 1];
                float* M = (idx < 300) ? A : U;
                float mp = M[i * 26 + p], mq = M[i * 26 + q];
                M[i * 26 + p] = c * mp - s * mq;
                M[i * 26 + q] = s * mp + c * mq;
            }
            __syncthreads();
        }
    }
    if (t < D2) lg[t] = logf(fmaxf(A[t * 26 + t], 1e-6f));
    __syncthreads();
    for (int f = t; f < D2 * D2; f += 64) {      // A <- U * diag(lg)
        int i = f / D2, k = f % D2;
        A[i * 26 + k] = U[i * 26 + k] * lg[k];
    }
    __syncthreads();
    for (int f = t; f < D2 * D2; f += 64) {      // out = (U diag lg) U^T
        int i = f / D2, j = f % D2;
        float a = 0.0f;
#pragma unroll
        for (int k = 0; k < D2; ++k) a += A[i * 26 + k] * U[j * 26 + k];
        out[(size_t)b * (D2 * D2) + f] = a;
    }
}

// ---------------------------------------------------------------------------
extern "C" void kernel_launch(void* const* d_in, const int* in_sizes, int n_in,
                              void* d_out, int out_size, void* d_ws, size_t ws_size,
                              hipStream_t stream) {
    const float* x  = (const float*)d_in[0];   // [2048,1,289,289]
    const float* W1 = (const float*)d_in[1];   // [100,289]
    const float* W2 = (const float*)d_in[2];   // [25,100]
    float* out = (float*)d_out;                // [2048,1,25,25]
    float* ws  = (float*)d_ws;

    // ws layout: W1T_pad (33280) | A2 (2048*625) | per-chunk T1T + S1
    const size_t W1T_FLOATS = (size_t)KPAD * WLD;          // 33280
    const size_t A2_FLOATS  = (size_t)NB * D2 * D2;        // 1,280,000
    const size_t PB_T1 = (size_t)KPAD * WLD;               // 33280 per batch (T1T)
    const size_t PB_S1 = (size_t)D1 * D1;                  // 10000 per batch
    const size_t PER_BATCH = PB_T1 + PB_S1;                // 43280

    float* w1t = ws;
    float* a2  = ws + W1T_FLOATS;
    float* rest = a2 + A2_FLOATS;

    size_t ws_floats = ws_size / sizeof(float);
    size_t rest_floats = (ws_floats > W1T_FLOATS + A2_FLOATS)
                           ? ws_floats - W1T_FLOATS - A2_FLOATS : 0;
    int C = (int)(rest_floats / PER_BATCH);
    if (C > NB) C = NB;
    if (C < 1) C = 1;   // assumes ws_size >= ~6 MB

    float* t1t = rest;
    float* s1  = rest + (size_t)C * PB_T1;

    prep_w1t<<<(int)(W1T_FLOATS / 256), 256, 0, stream>>>(W1, w1t);

    for (int base = 0; base < NB; base += C) {
        int c = NB - base; if (c > C) c = C;
        k1_wx<<<dim3(c, 4), 256, 0, stream>>>(x + (size_t)base * X_ELE, w1t, t1t);
        k2_tw<<<c, 256, 0, stream>>>(t1t, w1t, s1);
        k3_bimap2<<<c, 256, 0, stream>>>(s1, W2, a2 + (size_t)base * D2 * D2);
    }
    k4_logeig<<<NB, 64, 0, stream>>>(a2, out);
}

// Round 3
// 2147.442 us; speedup vs baseline: 1.3563x; 1.3563x over previous
//
#include <hip/hip_runtime.h>
#include <math.h>

// SPDNet pipeline: sinh(W2 sinh(W1 X W1^T) W2^T) -> logeig, B=2048, 289->100->25.
// K1/K2 use MFMA bf16 with a 3-term split (eps ~ 2^-25 <= fp32 mul rounding):
//   x = x1 + x2 + x3 (bf16 planes); x*y ~= x1y1 + x1y2 + x2y1 + x2y2 + x1y3 + x3y1
#define NB 2048
#define D0 289
#define D1 100
#define D2 25

typedef __bf16 bf16_t;
typedef __attribute__((ext_vector_type(8))) __bf16 bf16x8;
typedef __attribute__((ext_vector_type(4))) float f32x4;

#define WPL_STRIDE 40960      // one W plane: 128 rows x 320 k (bf16 elems)
#define T1_STRIDE  35840      // one T1 plane: 112 rows x 320 k
#define WPL_U16    (3*WPL_STRIDE)
#define T1_U16     (3*T1_STRIDE)

__device__ __forceinline__ void split3(float v, bf16_t& a, bf16_t& b, bf16_t& c) {
    a = (bf16_t)v;
    float r = v - (float)a;
    b = (bf16_t)r;
    r -= (float)b;
    c = (bf16_t)r;
}

// ---------------------------------------------------------------------------
// prep: W1 -> 3 bf16 planes [128][320], zero-padded (rows>=100, cols>=289 = 0).
// The zero padding is what makes all junk/clamped values downstream harmless.
__global__ __launch_bounds__(256) void prep_wpl(const float* __restrict__ W1,
                                                bf16_t* __restrict__ Wg) {
    int idx = blockIdx.x * 256 + threadIdx.x;          // 160 blocks -> 40960
    if (idx >= WPL_STRIDE) return;
    int m = idx / 320, k = idx % 320;
    float v = (m < D1 && k < D0) ? W1[m * D0 + k] : 0.0f;
    bf16_t h1, h2, h3; split3(v, h1, h2, h3);
    Wg[idx] = h1; Wg[WPL_STRIDE + idx] = h2; Wg[2 * WPL_STRIDE + idx] = h3;
}

// ---------------------------------------------------------------------------
// K1: T1 = W1 @ X[b]  (M=112 padded, N=64/block over 5 blocks, K=320)
// X is fp32 in global; converted to 3 bf16 planes tile-by-tile inside the
// kernel (saves the 1.7 GB prep round-trip). X symmetric => B[k][n]=X[n][k].
// LDS frag layout [pl][kkg][row][8k] = uniform 8 words/bank on ds_read_b128.
__global__ __launch_bounds__(256) void k1_mfma(const float* __restrict__ X,
                                               const bf16_t* __restrict__ Wg,
                                               bf16_t* __restrict__ T1g) {
    const int bb = blockIdx.x, n0 = blockIdx.y * 64;
    const int tid = threadIdx.x, l = tid & 63, w = tid >> 6;
    const int lm = l & 15, lk = l >> 4;
    __shared__ bf16_t sW[10752];   // 21504 B: pl*3584 + kkg*896 + m*8
    __shared__ bf16_t sX[6144];    // 12288 B: pl*2048 + kkg*512 + n*8
    const float* Xb = X + (size_t)bb * (size_t)(D0 * D0);

    f32x4 acc[7];
#pragma unroll
    for (int i = 0; i < 7; ++i) acc[i] = (f32x4){0.f, 0.f, 0.f, 0.f};

    // conversion slot (fixed per thread): row xn of the 64-row tile, k-group xkkg
    const int xn = tid >> 2, xkkg = tid & 3;
    int xr = n0 + xn; if (xr > 288) xr = 288;            // clamp: junk cols killed by W zeros
    const float* xrow = Xb + (size_t)xr * D0;

    for (int kt = 0; kt < 10; ++kt) {
        const int k0 = kt * 32;
        __syncthreads();
        // stage W tile: 1344 16B-slots (3 planes x 4 kgrp x 112 rows)
#pragma unroll
        for (int i = 0; i < 6; ++i) {
            int s = tid + 256 * i;
            if (s < 1344) {
                int pl = s / 448, r2 = s % 448, kkg = r2 / 112, m = r2 % 112;
                const uint4 d = *reinterpret_cast<const uint4*>(
                    Wg + pl * WPL_STRIDE + m * 320 + k0 + kkg * 8);
                *reinterpret_cast<uint4*>(&sW[pl * 3584 + kkg * 896 + m * 8]) = d;
            }
        }
        // convert + stage X tile: 8 consecutive fp32 -> 3x bf16x8, one b128/plane
        {
            int c0 = k0 + xkkg * 8;
            bf16x8 p1, p2, p3;
#pragma unroll
            for (int j = 0; j < 8; ++j) {
                int cj = c0 + j; if (cj > 288) cj = 288;  // clamp: k>=289 pairs with W zeros
                float v = xrow[cj];
                bf16_t h1, h2, h3; split3(v, h1, h2, h3);
                p1[j] = h1; p2[j] = h2; p3[j] = h3;
            }
            int dst = xkkg * 512 + xn * 8;
            *reinterpret_cast<bf16x8*>(&sX[dst]) = p1;
            *reinterpret_cast<bf16x8*>(&sX[2048 + dst]) = p2;
            *reinterpret_cast<bf16x8*>(&sX[4096 + dst]) = p3;
        }
        __syncthreads();
        // MFMA: per wave 7 m-tiles x 6 split-terms
        const int bo = lk * 512 + (w * 16 + lm) * 8;
        bf16x8 b1 = *reinterpret_cast<const bf16x8*>(&sX[bo]);
        bf16x8 b2 = *reinterpret_cast<const bf16x8*>(&sX[2048 + bo]);
        bf16x8 b3 = *reinterpret_cast<const bf16x8*>(&sX[4096 + bo]);
#pragma unroll
        for (int mt = 0; mt < 7; ++mt) {
            const int ao = lk * 896 + (mt * 16 + lm) * 8;
            bf16x8 a1 = *reinterpret_cast<const bf16x8*>(&sW[ao]);
            bf16x8 a2 = *reinterpret_cast<const bf16x8*>(&sW[3584 + ao]);
            bf16x8 a3 = *reinterpret_cast<const bf16x8*>(&sW[7168 + ao]);
            acc[mt] = __builtin_amdgcn_mfma_f32_16x16x32_bf16(a1, b1, acc[mt], 0, 0, 0);
            acc[mt] = __builtin_amdgcn_mfma_f32_16x16x32_bf16(a1, b2, acc[mt], 0, 0, 0);
            acc[mt] = __builtin_amdgcn_mfma_f32_16x16x32_bf16(a2, b1, acc[mt], 0, 0, 0);
            acc[mt] = __builtin_amdgcn_mfma_f32_16x16x32_bf16(a2, b2, acc[mt], 0, 0, 0);
            acc[mt] = __builtin_amdgcn_mfma_f32_16x16x32_bf16(a1, b3, acc[mt], 0, 0, 0);
            acc[mt] = __builtin_amdgcn_mfma_f32_16x16x32_bf16(a3, b1, acc[mt], 0, 0, 0);
        }
    }
    // epilogue: re-split fp32 acc into 3 bf16 T1 planes [112][320]
    bf16_t* Tb = T1g + (size_t)bb * T1_U16;
    const int col = n0 + w * 16 + lm;
#pragma unroll
    for (int mt = 0; mt < 7; ++mt)
#pragma unroll
        for (int r = 0; r < 4; ++r) {
            int row = mt * 16 + lk * 4 + r;
            bf16_t h1, h2, h3; split3(acc[mt][r], h1, h2, h3);
            Tb[row * 320 + col] = h1;
            Tb[T1_STRIDE + row * 320 + col] = h2;
            Tb[2 * T1_STRIDE + row * 320 + col] = h3;
        }
}

// ---------------------------------------------------------------------------
// K2: S1 = sinh(T1 @ W1^T)  (out 112x128 computed, 100x100 stored fp32)
// wave w covers n-tiles {w, w+4}; n-tiles 6..7 hit W's zero pad rows.
__global__ __launch_bounds__(256) void k2_mfma(const bf16_t* __restrict__ T1g,
                                               const bf16_t* __restrict__ Wg,
                                               float* __restrict__ S1) {
    const int bb = blockIdx.x;
    const int tid = threadIdx.x, l = tid & 63, w = tid >> 6;
    const int lm = l & 15, lk = l >> 4;
    __shared__ bf16_t sA[10752];   // T1 tile: pl*3584 + kkg*896 + m*8   (m<112)
    __shared__ bf16_t sB[12288];   // W tile:  pl*4096 + kkg*1024 + n*8  (n<128)
    const bf16_t* Tb = T1g + (size_t)bb * T1_U16;

    f32x4 acc[7][2];
#pragma unroll
    for (int i = 0; i < 7; ++i) {
        acc[i][0] = (f32x4){0.f, 0.f, 0.f, 0.f};
        acc[i][1] = (f32x4){0.f, 0.f, 0.f, 0.f};
    }

    for (int kt = 0; kt < 10; ++kt) {
        const int k0 = kt * 32;
        __syncthreads();
#pragma unroll
        for (int i = 0; i < 6; ++i) {
            int s = tid + 256 * i;
            if (s < 1344) {
                int pl = s / 448, r2 = s % 448, kkg = r2 / 112, m = r2 % 112;
                const uint4 d = *reinterpret_cast<const uint4*>(
                    Tb + pl * T1_STRIDE + m * 320 + k0 + kkg * 8);
                *reinterpret_cast<uint4*>(&sA[pl * 3584 + kkg * 896 + m * 8]) = d;
            }
        }
#pragma unroll
        for (int i = 0; i < 6; ++i) {
            int s = tid + 256 * i;                       // exactly 1536 slots
            int pl = s / 512, r2 = s % 512, kkg = r2 / 128, n = r2 % 128;
            const uint4 d = *reinterpret_cast<const uint4*>(
                Wg + pl * WPL_STRIDE + n * 320 + k0 + kkg * 8);
            *reinterpret_cast<uint4*>(&sB[pl * 4096 + kkg * 1024 + n * 8]) = d;
        }
        __syncthreads();
        bf16x8 bfr[2][3];
#pragma unroll
        for (int nj = 0; nj < 2; ++nj) {
            int bo = lk * 1024 + ((w + 4 * nj) * 16 + lm) * 8;
            bfr[nj][0] = *reinterpret_cast<const bf16x8*>(&sB[bo]);
            bfr[nj][1] = *reinterpret_cast<const bf16x8*>(&sB[4096 + bo]);
            bfr[nj][2] = *reinterpret_cast<const bf16x8*>(&sB[8192 + bo]);
        }
#pragma unroll
        for (int mt = 0; mt < 7; ++mt) {
            const int ao = lk * 896 + (mt * 16 + lm) * 8;
            bf16x8 a1 = *reinterpret_cast<const bf16x8*>(&sA[ao]);
            bf16x8 a2 = *reinterpret_cast<const bf16x8*>(&sA[3584 + ao]);
            bf16x8 a3 = *reinterpret_cast<const bf16x8*>(&sA[7168 + ao]);
#pragma unroll
            for (int nj = 0; nj < 2; ++nj) {
                acc[mt][nj] = __builtin_amdgcn_mfma_f32_16x16x32_bf16(a1, bfr[nj][0], acc[mt][nj], 0, 0, 0);
                acc[mt][nj] = __builtin_amdgcn_mfma_f32_16x16x32_bf16(a1, bfr[nj][1], acc[mt][nj], 0, 0, 0);
                acc[mt][nj] = __builtin_amdgcn_mfma_f32_16x16x32_bf16(a2, bfr[nj][0], acc[mt][nj], 0, 0, 0);
                acc[mt][nj] = __builtin_amdgcn_mfma_f32_16x16x32_bf16(a2, bfr[nj][1], acc[mt][nj], 0, 0, 0);
                acc[mt][nj] = __builtin_amdgcn_mfma_f32_16x16x32_bf16(a1, bfr[nj][2], acc[mt][nj], 0, 0, 0);
                acc[mt][nj] = __builtin_amdgcn_mfma_f32_16x16x32_bf16(a3, bfr[nj][0], acc[mt][nj], 0, 0, 0);
            }
        }
    }
#pragma unroll
    for (int mt = 0; mt < 7; ++mt)
#pragma unroll
        for (int nj = 0; nj < 2; ++nj) {
            int colg = (w + 4 * nj) * 16 + lm;
#pragma unroll
            for (int r = 0; r < 4; ++r) {
                int rowg = mt * 16 + lk * 4 + r;
                if (rowg < D1 && colg < D1)
                    S1[(size_t)bb * (D1 * D1) + rowg * D1 + colg] = sinhf(acc[mt][nj][r]);
            }
        }
}

// ---------------------------------------------------------------------------
// K3: A2[b] = sinh(W2 @ S1[b] @ W2^T)  (unchanged fp32)
__global__ __launch_bounds__(256) void k3_bimap2(const float* __restrict__ S1,
                                                 const float* __restrict__ W2,
                                                 float* __restrict__ A2) {
    __shared__ float S1s[D1 * 101];
    __shared__ float W2s[D2 * D1];
    __shared__ float T2s[D2 * 104];
    const int bb = blockIdx.x;
    const int tid = threadIdx.x;
    const float* Sb = S1 + (size_t)bb * (D1 * D1);

    for (int f = tid; f < D1 * D1; f += 256) {
        int i = f / D1, j = f % D1;
        S1s[i * 101 + j] = Sb[f];
    }
    for (int f = tid; f < D2 * D1; f += 256) W2s[f] = W2[f];
    __syncthreads();

    if (tid < 250) {
        int o = tid / 10, jg = tid % 10;
        float t2[10];
#pragma unroll
        for (int j = 0; j < 10; ++j) t2[j] = 0.0f;
        for (int i = 0; i < D1; ++i) {
            float w = W2s[o * D1 + i];
#pragma unroll
            for (int j = 0; j < 10; ++j) t2[j] += w * S1s[i * 101 + jg * 10 + j];
        }
#pragma unroll
        for (int j = 0; j < 10; ++j) T2s[o * 104 + jg * 10 + j] = t2[j];
    }
    __syncthreads();

    for (int f = tid; f < D2 * D2; f += 256) {
        int o = f / D2, p = f % D2;
        float a = 0.0f;
        for (int i = 0; i < D1; ++i) a += T2s[o * 104 + i] * W2s[p * D1 + i];
        A2[(size_t)bb * (D2 * D2) + f] = sinhf(a);
    }
}

// ---------------------------------------------------------------------------
// K4: batched 25x25 Jacobi eigensolve + U log(L) U^T. Now 128 threads/block.
#define SWEEPS 9
__global__ __launch_bounds__(128) void k4_logeig(const float* __restrict__ A2,
                                                 float* __restrict__ out) {
    __shared__ float A[D2 * 26];
    __shared__ float U[D2 * 26];
    __shared__ float cs[13 * 2];
    __shared__ float lg[D2];
    const int b = blockIdx.x;
    const int t = threadIdx.x;
    const float* G = A2 + (size_t)b * (D2 * D2);

    for (int f = t; f < D2 * 26; f += 128) {
        int i = f / 26, j = f % 26;
        if (j < D2) {
            A[f] = 0.5f * (G[i * D2 + j] + G[j * D2 + i]);
            U[f] = (i == j) ? 1.0f : 0.0f;
        } else { A[f] = 0.0f; U[f] = 0.0f; }
    }
    __syncthreads();

    for (int sw = 0; sw < SWEEPS; ++sw) {
        for (int r = 0; r < 25; ++r) {
            if (t >= 1 && t <= 12) {
                int p = (r + t) % 25, q = (r + 25 - t) % 25;
                float app = A[p * 26 + p], aqq = A[q * 26 + q], apq = A[p * 26 + q];
                float c = 1.0f, s = 0.0f;
                if (fabsf(apq) > 1e-30f) {
                    float tau = (aqq - app) / (2.0f * apq);
                    float sq = sqrtf(1.0f + tau * tau);
                    float tt = (tau >= 0.0f) ? 1.0f / (tau + sq) : 1.0f / (tau - sq);
                    c = 1.0f / sqrtf(1.0f + tt * tt);
                    s = tt * c;
                }
                cs[t * 2] = c; cs[t * 2 + 1] = s;
            }
            __syncthreads();
            for (int idx = t; idx < 300; idx += 128) {
                int pi = idx / 25 + 1, j = idx % 25;
                int p = (r + pi) % 25, q = (r + 25 - pi) % 25;
                float c = cs[pi * 2], s = cs[pi * 2 + 1];
                float ap = A[p * 26 + j], aq = A[q * 26 + j];
                A[p * 26 + j] = c * ap - s * aq;
                A[q * 26 + j] = s * ap + c * aq;
            }
            __syncthreads();
            for (int idx = t; idx < 600; idx += 128) {
                int pi = (idx % 300) / 25 + 1, i = idx % 25;
                int p = (r + pi) % 25, q = (r + 25 - pi) % 25;
                float c = cs[pi * 2], s = cs[pi * 2 + 1];
                float* M = (idx < 300) ? A : U;
                float mp = M[i * 26 + p], mq = M[i * 26 + q];
                M[i * 26 + p] = c * mp - s * mq;
                M[i * 26 + q] = s * mp + c * mq;
            }
            __syncthreads();
        }
    }
    if (t < D2) lg[t] = logf(fmaxf(A[t * 26 + t], 1e-6f));
    __syncthreads();
    for (int f = t; f < D2 * D2; f += 128) {
        int i = f / D2, k = f % D2;
        A[i * 26 + k] = U[i * 26 + k] * lg[k];
    }
    __syncthreads();
    for (int f = t; f < D2 * D2; f += 128) {
        int i = f / D2, j = f % D2;
        float a = 0.0f;
#pragma unroll
        for (int k = 0; k < D2; ++k) a += A[i * 26 + k] * U[j * 26 + k];
        out[(size_t)b * (D2 * D2) + f] = a;
    }
}

// ---------------------------------------------------------------------------
extern "C" void kernel_launch(void* const* d_in, const int* in_sizes, int n_in,
                              void* d_out, int out_size, void* d_ws, size_t ws_size,
                              hipStream_t stream) {
    const float* x  = (const float*)d_in[0];
    const float* W1 = (const float*)d_in[1];
    const float* W2 = (const float*)d_in[2];
    float* out = (float*)d_out;
    float* ws  = (float*)d_ws;

    // ws (floats): Wpl (61440) | A2 (1,280,000) | C x { T1 planes 53760 | S1 10000 }
    const size_t WPL_FL = WPL_U16 / 2;                 // 61440
    const size_t A2_FL  = (size_t)NB * D2 * D2;        // 1,280,000
    const size_t PB_T1  = T1_U16 / 2;                  // 53760
    const size_t PB_S1  = (size_t)D1 * D1;             // 10000
    const size_t PER_BATCH = PB_T1 + PB_S1;            // 63760

    bf16_t* wpl = (bf16_t*)ws;
    float*  a2  = ws + WPL_FL;
    float*  rest = a2 + A2_FL;

    size_t ws_floats = ws_size / sizeof(float);
    size_t rest_fl = (ws_floats > WPL_FL + A2_FL) ? ws_floats - WPL_FL - A2_FL : 0;
    int C = (int)(rest_fl / PER_BATCH);
    if (C > NB) C = NB;
    if (C < 1) C = 1;

    bf16_t* t1pl = (bf16_t*)rest;
    float*  s1   = rest + (size_t)C * PB_T1;

    prep_wpl<<<160, 256, 0, stream>>>(W1, wpl);

    for (int base = 0; base < NB; base += C) {
        int c = NB - base; if (c > C) c = C;
        k1_mfma<<<dim3(c, 5), 256, 0, stream>>>(x + (size_t)base * D0 * D0, wpl, t1pl);
        k2_mfma<<<c, 256, 0, stream>>>(t1pl, wpl, s1);
        k3_bimap2<<<c, 256, 0, stream>>>(s1, W2, a2 + (size_t)base * D2 * D2);
    }
    k4_logeig<<<NB, 128, 0, stream>>>(a2, out);
}